// Round 11
// baseline (557.886 us; speedup 1.0000x reference)
//
#include <hip/hip_runtime.h>

#define TT 1024
#define DD 32
#define HH 64

typedef __fp16 h2v __attribute__((ext_vector_type(2)));
typedef _Float16 f16x8 __attribute__((ext_vector_type(8)));
typedef float f32x4 __attribute__((ext_vector_type(4)));

struct __attribute__((aligned(16))) H4 { h2v p[4]; };
struct __attribute__((aligned(8)))  GX2 { h2v a, b; };

__device__ __forceinline__ h2v pk(float a, float b) {
    return __builtin_amdgcn_cvt_pkrtz(a, b);
}
__device__ __forceinline__ float fsig(float x) {
    float e = __builtin_amdgcn_exp2f(-1.4426950408889634f * x);
    return __builtin_amdgcn_rcpf(1.0f + e);
}
__device__ __forceinline__ float ftanh(float x) {
    float e = __builtin_amdgcn_exp2f(2.885390081777927f * x);
    return 1.0f - 2.0f * __builtin_amdgcn_rcpf(1.0f + e);
}
// barrier that orders LDS only: does NOT drain vmcnt, so global (gx) prefetches
// stay in flight across it. All cross-wave traffic in the loop is via LDS.
__device__ __forceinline__ void bar_lds() {
    asm volatile("s_waitcnt lgkmcnt(0)\n\ts_barrier" ::: "memory");
}
// select element (lane&3) of a C-fragment: 3 cndmasks
__device__ __forceinline__ float pick4(f32x4 c, bool s0, bool s1) {
    float lo = s0 ? c[1] : c[0];
    float hi = s0 ? c[3] : c[2];
    return s1 ? hi : lo;
}
// A-fragment: 8 consecutive fp32 weights -> packed f16 (lane holds A[m=lane&15][k=quad*8+i])
__device__ __forceinline__ f16x8 load_afrag(const float* p) {
    float4 f0 = *(const float4*)p;
    float4 f1 = *(const float4*)(p + 4);
    H4 t;
    t.p[0] = pk(f0.x, f0.y); t.p[1] = pk(f0.z, f0.w);
    t.p[2] = pk(f1.x, f1.y); t.p[3] = pk(f1.z, f1.w);
    return __builtin_bit_cast(f16x8, t);
}

#define MFMA16(A, B, C) __builtin_amdgcn_mfma_f32_16x16x32_f16(A, B, C, 0, 0, 0)

// ---------------------------------------------------------------------------
// Kernel 1 (unchanged): gx[b][t][j*4+q] = x[b][t].W_ih_l0[q*64+j] + biases (f16)
// ---------------------------------------------------------------------------
__global__ __launch_bounds__(256) void gx_precompute(
    const float* __restrict__ x, const float* __restrict__ w_ih_l0,
    const float* __restrict__ b_ih_l0, const float* __restrict__ b_hh_l0,
    __fp16* __restrict__ gx)
{
    const int blk = blockIdx.x;
    const int b   = blk >> 4;
    const int tq  = blk & 15;
    const int tid = threadIdx.x;
    const int q   = tid & 3;
    const int j   = tid >> 2;
    const int g   = q * 64 + j;

    __shared__ __attribute__((aligned(16))) h2v xlds[512];

    h2v wk[16];
    {
        const float4* wp = (const float4*)(w_ih_l0 + g * DD);
        #pragma unroll
        for (int i = 0; i < 8; ++i) {
            float4 f = wp[i];
            wk[2*i]   = pk(f.x, f.y);
            wk[2*i+1] = pk(f.z, f.w);
        }
    }
    const float bias = b_ih_l0[g] + b_hh_l0[g];

    const float* xb = x + (size_t)b * (TT*DD) + tq * 64 * DD;
    __fp16* gxo = gx + ((size_t)b * TT + tq * 64) * 256 + tid;

    #pragma unroll
    for (int sc = 0; sc < 2; ++sc) {
        __syncthreads();
        {
            float4 f = *(const float4*)(xb + sc * 1024 + tid * 4);
            xlds[tid*2]   = pk(f.x, f.y);
            xlds[tid*2+1] = pk(f.z, f.w);
        }
        __syncthreads();
        for (int tl = 0; tl < 32; ++tl) {
            float s0 = 0.f, s1 = 0.f;
            #pragma unroll
            for (int k = 0; k < 8; ++k) s0 = __builtin_amdgcn_fdot2(wk[k],   xlds[tl*16 + k],     s0, false);
            #pragma unroll
            for (int k = 0; k < 8; ++k) s1 = __builtin_amdgcn_fdot2(wk[8+k], xlds[tl*16 + 8 + k], s1, false);
            gxo[(sc*32 + tl) * 256] = (__fp16)(s0 + s1 + bias);
        }
    }
}

// ---------------------------------------------------------------------------
// Kernel 2: recurrence via MFMA (R10 structure) + LDS-only barrier + 2-deep
// gx prefetch ring.
// ---------------------------------------------------------------------------
__global__ __launch_bounds__(512) void lstm2_mfma(
    const float* __restrict__ w_hh_l0,
    const float* __restrict__ w_ih_l1, const float* __restrict__ w_hh_l1,
    const float* __restrict__ b_ih_l1, const float* __restrict__ b_hh_l1,
    const float* __restrict__ w_fc,   const float* __restrict__ b_fc,
    const __fp16* __restrict__ gx,
    float* __restrict__ out)
{
    const int b    = blockIdx.x;
    const int tid  = threadIdx.x;
    const int wave = tid >> 6;
    const int lane = tid & 63;
    const bool isL1 = wave < 4;
    const int w    = isL1 ? wave : (wave - 4);
    const int colg = lane & 15;
    const int quad = lane >> 4;
    const int j_act = 16*w + quad*4 + (lane & 3);

    __shared__ __attribute__((aligned(16))) __fp16 h1s[2][HH];
    __shared__ __attribute__((aligned(16))) __fp16 h2s[2][HH];
    if (tid < HH) {
        h1s[0][tid] = (__fp16)0.f; h1s[1][tid] = (__fp16)0.f;
        h2s[0][tid] = (__fp16)0.f; h2s[1][tid] = (__fp16)0.f;
    }

    f16x8 Aih[8], Ahh[8];
    float bias0 = 0.f, bias1 = 0.f, bias2 = 0.f, bias3 = 0.f;
    if (isL1) {
        #pragma unroll
        for (int q = 0; q < 4; ++q)
            #pragma unroll
            for (int kh = 0; kh < 2; ++kh)
                Ahh[q*2+kh] = load_afrag(w_hh_l0 + (size_t)(q*64 + 16*w + colg)*HH + kh*32 + quad*8);
    } else {
        #pragma unroll
        for (int q = 0; q < 4; ++q)
            #pragma unroll
            for (int kh = 0; kh < 2; ++kh) {
                Aih[q*2+kh] = load_afrag(w_ih_l1 + (size_t)(q*64 + 16*w + colg)*HH + kh*32 + quad*8);
                Ahh[q*2+kh] = load_afrag(w_hh_l1 + (size_t)(q*64 + 16*w + colg)*HH + kh*32 + quad*8);
            }
        bias0 = b_ih_l1[0*64 + j_act] + b_hh_l1[0*64 + j_act];
        bias1 = b_ih_l1[1*64 + j_act] + b_hh_l1[1*64 + j_act];
        bias2 = b_ih_l1[2*64 + j_act] + b_hh_l1[2*64 + j_act];
        bias3 = b_ih_l1[3*64 + j_act] + b_hh_l1[3*64 + j_act];
    }

    // gx stream (L1): 4 f16 per step = gates i,f,g,o of j_act; 2-deep ring.
    const __fp16* gxp = gx + ((size_t)b << 18) + j_act * 4;
    GX2 g0 = {}, g1 = {};
    if (isL1) {
        g0 = *(const GX2*)gxp;          // t = 0
        g1 = *(const GX2*)(gxp + 256);  // t = 1
    }

    const bool s0 = (lane & 1) != 0;
    const bool s1 = (lane & 2) != 0;
    float c = 0.0f;

    __syncthreads();

    for (int t = 0; t <= TT; ++t) {
        const int prev = (t + 1) & 1;
        const int cur  = t & 1;
        if (isL1) {
            if (t < TT) {
                // prefetch t+2 (stays in flight across the LDS-only barrier)
                const int tn2 = (t + 2 < TT) ? (t + 2) : (TT - 1);
                GX2 gn = *(const GX2*)(gxp + ((size_t)tn2 << 8));

                const __fp16* hp = &h1s[prev][0];
                f16x8 Blo = *(const f16x8*)(hp + quad*8);
                f16x8 Bhi = *(const f16x8*)(hp + 32 + quad*8);

                f32x4 Z = {0.f, 0.f, 0.f, 0.f};
                f32x4 C0 = Z, C1 = Z, C2 = Z, C3 = Z;
                C0 = MFMA16(Ahh[0], Blo, C0); C0 = MFMA16(Ahh[1], Bhi, C0);
                C1 = MFMA16(Ahh[2], Blo, C1); C1 = MFMA16(Ahh[3], Bhi, C1);
                C2 = MFMA16(Ahh[4], Blo, C2); C2 = MFMA16(Ahh[5], Bhi, C2);
                C3 = MFMA16(Ahh[6], Blo, C3); C3 = MFMA16(Ahh[7], Bhi, C3);

                float Si = pick4(C0, s0, s1) + (float)g0.a[0];
                float Sf = pick4(C1, s0, s1) + (float)g0.a[1];
                float Sg = pick4(C2, s0, s1) + (float)g0.b[0];
                float So = pick4(C3, s0, s1) + (float)g0.b[1];

                float ii = fsig(Si), ff = fsig(Sf), oo = fsig(So);
                float gg = ftanh(Sg);
                c = ff * c + ii * gg;
                float hv = oo * ftanh(c);
                if ((lane & 12) == 0) h1s[cur][j_act] = (__fp16)hv;
                g0 = g1; g1 = gn;
            }
        } else {
            if (t > 0) {
                const __fp16* hp1 = &h1s[prev][0];
                const __fp16* hp2 = &h2s[prev][0];
                f16x8 B1lo = *(const f16x8*)(hp1 + quad*8);
                f16x8 B1hi = *(const f16x8*)(hp1 + 32 + quad*8);
                f16x8 B2lo = *(const f16x8*)(hp2 + quad*8);
                f16x8 B2hi = *(const f16x8*)(hp2 + 32 + quad*8);

                f32x4 Z = {0.f, 0.f, 0.f, 0.f};
                f32x4 C0 = Z, C1 = Z, C2 = Z, C3 = Z;
                C0 = MFMA16(Aih[0], B1lo, C0); C0 = MFMA16(Aih[1], B1hi, C0);
                C0 = MFMA16(Ahh[0], B2lo, C0); C0 = MFMA16(Ahh[1], B2hi, C0);
                C1 = MFMA16(Aih[2], B1lo, C1); C1 = MFMA16(Aih[3], B1hi, C1);
                C1 = MFMA16(Ahh[2], B2lo, C1); C1 = MFMA16(Ahh[3], B2hi, C1);
                C2 = MFMA16(Aih[4], B1lo, C2); C2 = MFMA16(Aih[5], B1hi, C2);
                C2 = MFMA16(Ahh[4], B2lo, C2); C2 = MFMA16(Ahh[5], B2hi, C2);
                C3 = MFMA16(Aih[6], B1lo, C3); C3 = MFMA16(Aih[7], B1hi, C3);
                C3 = MFMA16(Ahh[6], B2lo, C3); C3 = MFMA16(Ahh[7], B2hi, C3);

                float Si = pick4(C0, s0, s1) + bias0;
                float Sf = pick4(C1, s0, s1) + bias1;
                float Sg = pick4(C2, s0, s1) + bias2;
                float So = pick4(C3, s0, s1) + bias3;

                float ii = fsig(Si), ff = fsig(Sf), oo = fsig(So);
                float gg = ftanh(Sg);
                c = ff * c + ii * gg;
                float hv = oo * ftanh(c);
                if ((lane & 12) == 0) h2s[cur][j_act] = (__fp16)hv;
            }
        }
        bar_lds();
    }

    // h2(T-1) is in h2s[0] (last write at t=1024, cur=0). FC + sigmoid.
    if (tid < HH) {
        float v = (float)h2s[0][tid] * w_fc[tid];
        #pragma unroll
        for (int off = 32; off > 0; off >>= 1) v += __shfl_down(v, off);
        if (tid == 0) out[b] = fsig(v + b_fc[0]);
    }
}

extern "C" void kernel_launch(void* const* d_in, const int* in_sizes, int n_in,
                              void* d_out, int out_size, void* d_ws, size_t ws_size,
                              hipStream_t stream) {
    __fp16* gx = (__fp16*)d_ws;   // 134 MB, ws_size verified sufficient
    gx_precompute<<<dim3(256 * 16), dim3(256), 0, stream>>>(
        (const float*)d_in[0], (const float*)d_in[1],
        (const float*)d_in[3], (const float*)d_in[4], gx);
    lstm2_mfma<<<dim3(256), dim3(512), 0, stream>>>(
        (const float*)d_in[2],
        (const float*)d_in[5], (const float*)d_in[6],
        (const float*)d_in[7], (const float*)d_in[8],
        (const float*)d_in[9], (const float*)d_in[10],
        gx, (float*)d_out);
}

// Round 12
// 545.418 us; speedup vs baseline: 1.0229x; 1.0229x over previous
//
#include <hip/hip_runtime.h>

#define TT 1024
#define DD 32
#define HH 64

typedef __fp16 h2v __attribute__((ext_vector_type(2)));
typedef _Float16 f16x8 __attribute__((ext_vector_type(8)));
typedef float f32x4 __attribute__((ext_vector_type(4)));

struct __attribute__((aligned(16))) H4 { h2v p[4]; };

__device__ __forceinline__ h2v pk(float a, float b) {
    return __builtin_amdgcn_cvt_pkrtz(a, b);
}
__device__ __forceinline__ float fsig(float x) {
    float e = __builtin_amdgcn_exp2f(-1.4426950408889634f * x);
    return __builtin_amdgcn_rcpf(1.0f + e);
}
__device__ __forceinline__ float ftanh(float x) {
    float e = __builtin_amdgcn_exp2f(2.885390081777927f * x);
    return 1.0f - 2.0f * __builtin_amdgcn_rcpf(1.0f + e);
}
// select reg r (r = s1*2+s0) of a C-fragment: 3 cndmasks
__device__ __forceinline__ float pick4(f32x4 c, bool s0, bool s1) {
    float lo = s0 ? c[1] : c[0];
    float hi = s0 ? c[3] : c[2];
    return s1 ? hi : lo;
}
// A-fragment: 8 consecutive fp32 weights -> packed f16 (lane = A[m=lane&15][k=quad*8+i])
__device__ __forceinline__ f16x8 load_afrag(const float* p) {
    float4 f0 = *(const float4*)p;
    float4 f1 = *(const float4*)(p + 4);
    H4 t;
    t.p[0] = pk(f0.x, f0.y); t.p[1] = pk(f0.z, f0.w);
    t.p[2] = pk(f1.x, f1.y); t.p[3] = pk(f1.z, f1.w);
    return __builtin_bit_cast(f16x8, t);
}
#define MFMA16(A, B, C) __builtin_amdgcn_mfma_f32_16x16x32_f16(A, B, C, 0, 0, 0)

// ---------------------------------------------------------------------------
// One kernel, 64 blocks x 512 threads; block = 4 batch elements.
// Waves 0-3: L1 (j-slice = wave). Waves 4-7: L2 (one step behind), wave 7 also
// stages x(t+1) into LDS (fp32->f16) with a 2-deep register prefetch ring.
//
// LDS buffer per parity: 5 chunks x [4 batch][4 quad][8 f16]:
//   chunk 0     = x(t)          (K 0..31 of L1)
//   chunks 1,2  = h1(t-1)       (K 32..95 of L1; K 0..63 of L2)
//   chunks 3,4  = h2(t-2)       (K 64..127 of L2)
// B-operand trick: 16 MFMA cols = 4 batches replicated 4x (col&3 = batch).
// C layout (m89): col=lane&15, row=quad*4+reg  ->  lane L owns the UNIQUE cell
// (j = js*16 + quad*4 + ((L>>2)&3), batch = L&3): every lane does one distinct
// cell update, every lane writes one distinct h value. No redundancy.
// ---------------------------------------------------------------------------
__global__ __launch_bounds__(512) void lstm2_b4(
    const float* __restrict__ x,
    const float* __restrict__ w_ih_l0, const float* __restrict__ w_hh_l0,
    const float* __restrict__ b_ih_l0, const float* __restrict__ b_hh_l0,
    const float* __restrict__ w_ih_l1, const float* __restrict__ w_hh_l1,
    const float* __restrict__ b_ih_l1, const float* __restrict__ b_hh_l1,
    const float* __restrict__ w_fc,   const float* __restrict__ b_fc,
    float* __restrict__ out)
{
    const int bbase = blockIdx.x * 4;
    const int tid  = threadIdx.x;
    const int wave = tid >> 6;
    const int lane = tid & 63;
    const bool isL1 = wave < 4;
    const int js   = wave & 3;          // j-slice (16 j's)
    const int quad = lane >> 4;
    const int bb   = lane & 3;          // batch within block
    const int rsel = (lane >> 2) & 3;   // C-reg select
    const int jj   = js*16 + quad*4 + rsel;  // this lane's cell j
    const int mrow = lane & 15;         // A-operand row within tile

    __shared__ __attribute__((aligned(16))) __fp16 buf[1280];  // [2][5][4][4][8]

    // zero both parities (h chunks must start at 0; chunk 0 overwritten below)
    {
        int* bi = (int*)buf;
        bi[tid] = 0;
        if (tid < 128) bi[512 + tid] = 0;
    }

    // ---- A fragments (weights), biases ----
    f16x8 A[16];
    float bs0, bs1, bs2, bs3;
    if (isL1) {
        #pragma unroll
        for (int q = 0; q < 4; ++q) {
            const int g = q*64 + js*16 + mrow;
            A[q*3 + 0] = load_afrag(w_ih_l0 + (size_t)g*DD + quad*8);
            A[q*3 + 1] = load_afrag(w_hh_l0 + (size_t)g*HH + quad*8);
            A[q*3 + 2] = load_afrag(w_hh_l0 + (size_t)g*HH + 32 + quad*8);
        }
        bs0 = b_ih_l0[0*64 + jj] + b_hh_l0[0*64 + jj];
        bs1 = b_ih_l0[1*64 + jj] + b_hh_l0[1*64 + jj];
        bs2 = b_ih_l0[2*64 + jj] + b_hh_l0[2*64 + jj];
        bs3 = b_ih_l0[3*64 + jj] + b_hh_l0[3*64 + jj];
    } else {
        #pragma unroll
        for (int q = 0; q < 4; ++q) {
            const int g = q*64 + js*16 + mrow;
            A[q*4 + 0] = load_afrag(w_ih_l1 + (size_t)g*HH + quad*8);
            A[q*4 + 1] = load_afrag(w_ih_l1 + (size_t)g*HH + 32 + quad*8);
            A[q*4 + 2] = load_afrag(w_hh_l1 + (size_t)g*HH + quad*8);
            A[q*4 + 3] = load_afrag(w_hh_l1 + (size_t)g*HH + 32 + quad*8);
        }
        bs0 = b_ih_l1[0*64 + jj] + b_hh_l1[0*64 + jj];
        bs1 = b_ih_l1[1*64 + jj] + b_hh_l1[1*64 + jj];
        bs2 = b_ih_l1[2*64 + jj] + b_hh_l1[2*64 + jj];
        bs3 = b_ih_l1[3*64 + jj] + b_hh_l1[3*64 + jj];
    }

    // per-lane LDS offsets (f16 units)
    const int roff = (bb*4 + quad)*8;                         // B-frag read
    const int cw   = (isL1 ? 1 : 3) + (jj >> 5);              // h write chunk
    const int woff = ((cw*4 + bb)*4 + ((jj & 31) >> 3))*8 + (jj & 7);

    // x stager (wave 7): lane -> (batch = lane>>4, k-pair = lane&15)
    const float* xg = x + (size_t)(bbase + (lane >> 4)) * (TT*DD) + (lane & 15)*2;
    const int sdw = ((lane >> 4)*4 + ((lane & 15) >> 2))*4 + ((lane & 15) & 3);
    float2 xv1 = {0.f, 0.f}, xv2 = {0.f, 0.f};

    __syncthreads();   // zero-init visible before x(0) staging
    if (wave == 7) {
        float2 v0 = *(const float2*)xg;                       // x(0)
        ((int*)buf)[sdw] = __builtin_bit_cast(int, pk(v0.x, v0.y));
        xv1 = *(const float2*)(xg + DD);                      // x(1)
        xv2 = *(const float2*)(xg + 2*DD);                    // x(2)
    }
    __syncthreads();

    const bool s0 = (rsel & 1) != 0;
    const bool s1 = (rsel & 2) != 0;
    float cst = 0.0f;

    for (int t = 0; t <= TT; ++t) {
        const int p = t & 1;
        const __fp16* bc = buf + p*640;
        __fp16* bn = buf + (p ^ 1)*640;
        if (isL1) {
            if (t < TT) {
                f16x8 B0 = *(const f16x8*)(bc + 0*128 + roff);
                f16x8 B1 = *(const f16x8*)(bc + 1*128 + roff);
                f16x8 B2 = *(const f16x8*)(bc + 2*128 + roff);

                f32x4 Z = {0.f, 0.f, 0.f, 0.f};
                f32x4 C0 = Z, C1 = Z, C2 = Z, C3 = Z;
                C0 = MFMA16(A[0], B0, C0); C0 = MFMA16(A[1],  B1, C0); C0 = MFMA16(A[2],  B2, C0);
                C1 = MFMA16(A[3], B0, C1); C1 = MFMA16(A[4],  B1, C1); C1 = MFMA16(A[5],  B2, C1);
                C2 = MFMA16(A[6], B0, C2); C2 = MFMA16(A[7],  B1, C2); C2 = MFMA16(A[8],  B2, C2);
                C3 = MFMA16(A[9], B0, C3); C3 = MFMA16(A[10], B1, C3); C3 = MFMA16(A[11], B2, C3);

                float Si = pick4(C0, s0, s1) + bs0;
                float Sf = pick4(C1, s0, s1) + bs1;
                float Sg = pick4(C2, s0, s1) + bs2;
                float So = pick4(C3, s0, s1) + bs3;

                float ii = fsig(Si), ff = fsig(Sf), oo = fsig(So);
                float gg = ftanh(Sg);
                cst = ff * cst + ii * gg;
                float hv = oo * ftanh(cst);
                bn[woff] = (__fp16)hv;
            }
        } else {
            if (wave == 7 && t < TT) {   // stage x(t+1) into next buffer
                ((int*)bn)[sdw] = __builtin_bit_cast(int, pk(xv1.x, xv1.y));
                xv1 = xv2;
                const int tl = (t + 3 < TT) ? (t + 3) : (TT - 1);
                xv2 = *(const float2*)(xg + (size_t)tl*DD);
            }
            if (t > 0) {
                f16x8 B1 = *(const f16x8*)(bc + 1*128 + roff);
                f16x8 B2 = *(const f16x8*)(bc + 2*128 + roff);
                f16x8 B3 = *(const f16x8*)(bc + 3*128 + roff);
                f16x8 B4 = *(const f16x8*)(bc + 4*128 + roff);

                f32x4 Z = {0.f, 0.f, 0.f, 0.f};
                f32x4 C0 = Z, C1 = Z, C2 = Z, C3 = Z;
                C0 = MFMA16(A[0],  B1, C0); C0 = MFMA16(A[1],  B2, C0);
                C0 = MFMA16(A[2],  B3, C0); C0 = MFMA16(A[3],  B4, C0);
                C1 = MFMA16(A[4],  B1, C1); C1 = MFMA16(A[5],  B2, C1);
                C1 = MFMA16(A[6],  B3, C1); C1 = MFMA16(A[7],  B4, C1);
                C2 = MFMA16(A[8],  B1, C2); C2 = MFMA16(A[9],  B2, C2);
                C2 = MFMA16(A[10], B3, C2); C2 = MFMA16(A[11], B4, C2);
                C3 = MFMA16(A[12], B1, C3); C3 = MFMA16(A[13], B2, C3);
                C3 = MFMA16(A[14], B3, C3); C3 = MFMA16(A[15], B4, C3);

                float Si = pick4(C0, s0, s1) + bs0;
                float Sf = pick4(C1, s0, s1) + bs1;
                float Sg = pick4(C2, s0, s1) + bs2;
                float So = pick4(C3, s0, s1) + bs3;

                float ii = fsig(Si), ff = fsig(Sf), oo = fsig(So);
                float gg = ftanh(Sg);
                cst = ff * cst + ii * gg;
                float hv = oo * ftanh(cst);
                bn[woff] = (__fp16)hv;
            }
        }
        __syncthreads();
    }

    // h2(TT-1) sits in buf parity 1, chunks 3,4. FC + sigmoid (wave 0).
    if (wave == 0) {
        const int jg = lane >> 2;   // 0..15
        float s = 0.f;
        #pragma unroll
        for (int u2 = 0; u2 < 4; ++u2) {
            const int j = jg*4 + u2;
            float hval = (float)buf[640 + (((3 + (j >> 5))*4 + bb)*4 + ((j & 31) >> 3))*8 + (j & 7)];
            s += hval * w_fc[j];
        }
        s += __shfl_xor(s, 4);
        s += __shfl_xor(s, 8);
        s += __shfl_xor(s, 16);
        s += __shfl_xor(s, 32);
        if (lane < 4) out[bbase + lane] = fsig(s + b_fc[0]);
    }
}

extern "C" void kernel_launch(void* const* d_in, const int* in_sizes, int n_in,
                              void* d_out, int out_size, void* d_ws, size_t ws_size,
                              hipStream_t stream) {
    lstm2_b4<<<dim3(64), dim3(512), 0, stream>>>(
        (const float*)d_in[0],
        (const float*)d_in[1], (const float*)d_in[2],
        (const float*)d_in[3], (const float*)d_in[4],
        (const float*)d_in[5], (const float*)d_in[6],
        (const float*)d_in[7], (const float*)d_in[8],
        (const float*)d_in[9], (const float*)d_in[10],
        (float*)d_out);
}